// Round 11
// baseline (24.173 us; speedup 1.0000x reference)
//
#include <hip/hip_runtime.h>

#define NQ 8
#define NLAYERS 3

typedef unsigned int uint2ev __attribute__((ext_vector_type(2)));

// ---- lane xor exchange within 32-lane halves, zero DS ops ----
// masks 1,2 -> quad_perm; 4 -> row_shr/shl:4 + select; 8 -> row_ror:8;
// 16 -> permlane16_swap (lane^16, stays within each 32-half).
template<int MASK>
__device__ __forceinline__ float xorlane(float v, int r) {
    if constexpr (MASK == 1) {
        return __int_as_float(__builtin_amdgcn_mov_dpp(__float_as_int(v), 0xB1, 0xF, 0xF, false)); // quad_perm [1,0,3,2]
    } else if constexpr (MASK == 2) {
        return __int_as_float(__builtin_amdgcn_mov_dpp(__float_as_int(v), 0x4E, 0xF, 0xF, false)); // quad_perm [2,3,0,1]
    } else if constexpr (MASK == 4) {
        float a = __int_as_float(__builtin_amdgcn_update_dpp(0, __float_as_int(v), 0x114, 0xF, 0xF, false)); // row_shr:4
        float b = __int_as_float(__builtin_amdgcn_update_dpp(0, __float_as_int(v), 0x104, 0xF, 0xF, false)); // row_shl:4
        return (r & 4) ? a : b;
    } else if constexpr (MASK == 8) {
        return __int_as_float(__builtin_amdgcn_mov_dpp(__float_as_int(v), 0x128, 0xF, 0xF, false)); // row_ror:8 == xor 8
    } else if constexpr (MASK == 16) {
        uint2ev rr = __builtin_amdgcn_permlane16_swap(__float_as_uint(v), __float_as_uint(v), false, false);
        return __uint_as_float((r & 16) ? rr.x : rr.y);
    }
}

// ---- DPP-fused 32-lane sum; total lands in lane r=31 of each half ----
template<int CTRL>
__device__ __forceinline__ float dpp_add_stage(float v) {
    int moved = __builtin_amdgcn_update_dpp(0, __float_as_int(v), CTRL, 0xF, 0xF, false);
    return v + __int_as_float(moved);
}
__device__ __forceinline__ float halfsum31(float v) {
    v = dpp_add_stage<0x111>(v);   // row_shr:1
    v = dpp_add_stage<0x112>(v);   // row_shr:2
    v = dpp_add_stage<0x114>(v);   // row_shr:4
    v = dpp_add_stage<0x118>(v);   // row_shr:8
    v = dpp_add_stage<0x142>(v);   // row_bcast:15 -> lane31 (and 63) = 32-half total
    return v;
}

__device__ __forceinline__ void ry_pair(float c, float s, float& a0, float& a1) {
    float n0 = c * a0 - s * a1;
    float n1 = s * a0 + c * a1;
    a0 = n0; a1 = n1;
}

__device__ __forceinline__ void rz_amp(float cp, float ssp, float& re, float& im) {
    float nr = re * cp - im * ssp;
    float ni = im * cp + re * ssp;
    re = nr; im = ni;
}

// qubits 0..2 -> j bits 0..2 (8 amps/lane); qubits 3..7 -> half-lane bits r0..r4
template<int Q>
__device__ __forceinline__ void ry8(float c, float s, float ar[8], float ai[8], int r) {
    if constexpr (Q < 3) {
        constexpr int M = 1 << Q;
#pragma unroll
        for (int j = 0; j < 8; ++j) if (!(j & M)) {
            ry_pair(c, s, ar[j], ar[j | M]);
            ry_pair(c, s, ai[j], ai[j | M]);
        }
    } else {
        constexpr int LM = 1 << (Q - 3);
        float sgn = (r & LM) ? s : -s;
#pragma unroll
        for (int j = 0; j < 8; ++j) {
            float pr = xorlane<LM>(ar[j], r);
            float pi = xorlane<LM>(ai[j], r);
            ar[j] = c * ar[j] + sgn * pr;
            ai[j] = c * ai[j] + sgn * pi;
        }
    }
}

template<int Q>
__device__ __forceinline__ void rz8(float cp, float sp, float ar[8], float ai[8], int r) {
    if constexpr (Q < 3) {
#pragma unroll
        for (int j = 0; j < 8; ++j) {
            float ssp = ((j >> Q) & 1) ? sp : -sp;   // compile-time sign per j
            rz_amp(cp, ssp, ar[j], ai[j]);
        }
    } else {
        float ssp = (r & (1 << (Q - 3))) ? sp : -sp;
#pragma unroll
        for (int j = 0; j < 8; ++j) rz_amp(cp, ssp, ar[j], ai[j]);
    }
}

#define SWAP2(a, b) { float _t = a; a = b; b = _t; }

// ring1: CNOT(0,1),(1,2),(2,3),(3,4),(4,5),(5,6),(6,7),(7,0) in 8-amp layout
__device__ __forceinline__ void ring8(float ar[8], float ai[8], int r) {
    // (0,1): ctrl j0 -> flip j1: swap (1,3),(5,7)
    SWAP2(ar[1], ar[3]); SWAP2(ai[1], ai[3]);
    SWAP2(ar[5], ar[7]); SWAP2(ai[5], ai[7]);
    // (1,2): ctrl j1 -> flip j2: swap (2,6),(3,7)
    SWAP2(ar[2], ar[6]); SWAP2(ai[2], ai[6]);
    SWAP2(ar[3], ar[7]); SWAP2(ai[3], ai[7]);
    // (2,3): ctrl j2 (j=4..7) -> flip r0: unconditional exchange mask1
#pragma unroll
    for (int j = 4; j < 8; ++j) {
        ar[j] = xorlane<1>(ar[j], r);
        ai[j] = xorlane<1>(ai[j], r);
    }
    // (3,4): ctrl r0, tgt r1
    {
        bool hi = (r & 1) != 0;
#pragma unroll
        for (int j = 0; j < 8; ++j) {
            float pr = xorlane<2>(ar[j], r);
            float pi = xorlane<2>(ai[j], r);
            ar[j] = hi ? pr : ar[j];
            ai[j] = hi ? pi : ai[j];
        }
    }
    // (4,5): ctrl r1, tgt r2
    {
        bool hi = (r & 2) != 0;
#pragma unroll
        for (int j = 0; j < 8; ++j) {
            float pr = xorlane<4>(ar[j], r);
            float pi = xorlane<4>(ai[j], r);
            ar[j] = hi ? pr : ar[j];
            ai[j] = hi ? pi : ai[j];
        }
    }
    // (5,6): ctrl r2, tgt r3
    {
        bool hi = (r & 4) != 0;
#pragma unroll
        for (int j = 0; j < 8; ++j) {
            float pr = xorlane<8>(ar[j], r);
            float pi = xorlane<8>(ai[j], r);
            ar[j] = hi ? pr : ar[j];
            ai[j] = hi ? pi : ai[j];
        }
    }
    // (6,7): ctrl r3, tgt r4
    {
        bool hi = (r & 8) != 0;
#pragma unroll
        for (int j = 0; j < 8; ++j) {
            float pr = xorlane<16>(ar[j], r);
            float pi = xorlane<16>(ai[j], r);
            ar[j] = hi ? pr : ar[j];
            ai[j] = hi ? pi : ai[j];
        }
    }
    // (7,0): ctrl r4, tgt j0: lanes r4=1 swap local pairs j <-> j^1
    {
        bool hi = (r & 16) != 0;
#pragma unroll
        for (int j = 0; j < 8; j += 2) {
            float t0r = ar[j], t1r = ar[j + 1];
            ar[j]     = hi ? t1r : t0r;
            ar[j + 1] = hi ? t0r : t1r;
            float t0i = ai[j], t1i = ai[j + 1];
            ai[j]     = hi ? t1i : t0i;
            ai[j + 1] = hi ? t0i : t1i;
        }
    }
}

#define CMUL(rr, ri, xr, xi, yr, yi) { float _tr = (xr)*(yr) - (xi)*(yi); \
                                       float _ti = (xr)*(yi) + (xi)*(yr); \
                                       rr = _tr; ri = _ti; }

// ============ FUSED: circuit (2 samples/wave, 8 amps/lane) + MLP, 8 samples/block ============
// Exact reductions (carried, re-derived for 3-local-bit layout):
//  ring0 fold selectors: s0=j0^r4, s1=j0^j1^r4, s2=j1^j2, s3=j2^r0,
//                        s4=r0^r1, s5=r1^r2, s6=r2^r3, s7=r3^r4
//  ring2+RZ2 fold: m0=0xFE -> G12 * pr(r0..r4); m_q=2^{q+1}-1 ->
//                  G01 (q=1), G012 (q>=2) * r-prefix parities.
__global__ __launch_bounds__(256) void qfused(
    const float* __restrict__ x,        // [B,8]
    const float* __restrict__ qw,       // [3,8,2]
    const float* __restrict__ W1,       // [8,64]
    const float* __restrict__ b1,       // [64]
    const float* __restrict__ W2,       // [64,256]
    const float* __restrict__ b2,       // [256]
    float* __restrict__ out,            // [B,256]
    int B)
{
    __shared__ float4 tab[NLAYERS * NQ];
    __shared__ float z_lds[8][8];
    __shared__ float h_lds[8][64];

    int tid = threadIdx.x;
    if (tid < NLAYERS * NQ) {
        float w0 = 0.5f * qw[tid * 2 + 0];
        float w1 = 0.5f * qw[tid * 2 + 1];
        if (tid < 8)
            tab[tid] = make_float4(w0, 0.f, __cosf(w1), __sinf(w1));
        else
            tab[tid] = make_float4(__cosf(w0), __sinf(w0), __cosf(w1), __sinf(w1));
    }
    __syncthreads();

    int lane = tid & 63;
    int wid  = tid >> 6;
    int g    = lane >> 5;               // sample group in wave (0,1)
    int r    = lane & 31;               // half-lane bits r0..r4
    int sl   = wid * 2 + g;             // sample slot in block (0..7)
    int sbase = blockIdx.x * 8;
    int sample = sbase + sl;
    if (sample >= B) sample = B - 1;    // clamp: all threads reach barriers

    // ---- per-lane encode ----
    const float4* x4 = (const float4*)(x + sample * 8);
    float4 xa = x4[0], xb = x4[1];
    float xs[8] = {xa.x, xa.y, xa.z, xa.w, xb.x, xb.y, xb.z, xb.w};
    float xmin = xs[0], xmax = xs[0];
#pragma unroll
    for (int q = 1; q < 8; ++q) {
        xmin = fminf(xmin, xs[q]);
        xmax = fmaxf(xmax, xs[q]);
    }
    float inv_pi2 = 1.5707963267948966f / (xmax - xmin + 1e-8f);

    float cc[8], ss[8], cw[8], sw[8];
#pragma unroll
    for (int q = 0; q < 8; ++q) {
        float4 t0 = tab[q];
        float a = fmaf(xs[q] - xmin, inv_pi2, t0.x);
        __sincosf(a, &ss[q], &cc[q]);
        cw[q] = t0.z;
        sw[q] = t0.w;
    }

    // f_q(b) = ((b? ss:cc)*cw, (b? +1:-1)*(b? ss:cc)*sw)
    int u4 = (r >> 4) & 1;              // r4
    int w0v = r & 1;                    // r0

    float X0r[2], X0i[2], X1r[2], X1i[2], X2r[2], X2i[2], X3r[2], X3i[2];
#pragma unroll
    for (int k = 0; k < 2; ++k) {
        { int b = k ^ u4;  float rr = b ? ss[0] : cc[0];
          X0r[k] = rr * cw[0]; X0i[k] = (b ? rr : -rr) * sw[0]; }
        { int b = k ^ u4;  float rr = b ? ss[1] : cc[1];
          X1r[k] = rr * cw[1]; X1i[k] = (b ? rr : -rr) * sw[1]; }
        { int b = k;       float rr = b ? ss[2] : cc[2];
          X2r[k] = rr * cw[2]; X2i[k] = (b ? rr : -rr) * sw[2]; }
        { int b = k ^ w0v; float rr = b ? ss[3] : cc[3];
          X3r[k] = rr * cw[3]; X3i[k] = (b ? rr : -rr) * sw[3]; }
    }

    // plane = f4(r0^r1) * f5(r1^r2) * f6(r2^r3) * f7(r3^r4)
    float plr, pli;
    {
        int b4 = (r ^ (r >> 1)) & 1;
        int b5 = ((r >> 1) ^ (r >> 2)) & 1;
        int b6 = ((r >> 2) ^ (r >> 3)) & 1;
        int b7 = ((r >> 3) ^ (r >> 4)) & 1;
        float r4_ = b4 ? ss[4] : cc[4];
        float f4r = r4_ * cw[4], f4i = (b4 ? r4_ : -r4_) * sw[4];
        float r5_ = b5 ? ss[5] : cc[5];
        float f5r = r5_ * cw[5], f5i = (b5 ? r5_ : -r5_) * sw[5];
        float r6_ = b6 ? ss[6] : cc[6];
        float f6r = r6_ * cw[6], f6i = (b6 ? r6_ : -r6_) * sw[6];
        float r7_ = b7 ? ss[7] : cc[7];
        float f7r = r7_ * cw[7], f7i = (b7 ? r7_ : -r7_) * sw[7];
        CMUL(plr, pli, f4r, f4i, f5r, f5i);
        CMUL(plr, pli, plr, pli, f6r, f6i);
        CMUL(plr, pli, plr, pli, f7r, f7i);
    }

    // PT[j0][j1] = plane * X0[j0] * X1[j0^j1];  S[j1][j2] = X2[j1^j2] * X3[j2]
    float PTr[2][2], PTi[2][2];
    {
        float t0r, t0i, t1r, t1i;
        CMUL(t0r, t0i, plr, pli, X0r[0], X0i[0]);
        CMUL(t1r, t1i, plr, pli, X0r[1], X0i[1]);
        CMUL(PTr[0][0], PTi[0][0], t0r, t0i, X1r[0], X1i[0]);
        CMUL(PTr[0][1], PTi[0][1], t0r, t0i, X1r[1], X1i[1]);
        CMUL(PTr[1][0], PTi[1][0], t1r, t1i, X1r[1], X1i[1]);
        CMUL(PTr[1][1], PTi[1][1], t1r, t1i, X1r[0], X1i[0]);
    }
    float Sr[2][2], Si[2][2];
    CMUL(Sr[0][0], Si[0][0], X2r[0], X2i[0], X3r[0], X3i[0]);
    CMUL(Sr[0][1], Si[0][1], X2r[1], X2i[1], X3r[1], X3i[1]);
    CMUL(Sr[1][0], Si[1][0], X2r[1], X2i[1], X3r[0], X3i[0]);
    CMUL(Sr[1][1], Si[1][1], X2r[0], X2i[0], X3r[1], X3i[1]);

    float ar[8], ai[8];
#pragma unroll
    for (int j2 = 0; j2 < 2; ++j2)
#pragma unroll
        for (int j1 = 0; j1 < 2; ++j1)
#pragma unroll
            for (int j0 = 0; j0 < 2; ++j0) {
                int j = j0 + 2 * j1 + 4 * j2;
                CMUL(ar[j], ai[j], PTr[j0][j1], PTi[j0][j1], Sr[j1][j2], Si[j1][j2]);
            }

    // ---- layer 1: RY + RZ ----
    {
        float4 t;
        t = tab[8];  ry8<0>(t.x, t.y, ar, ai, r); rz8<0>(t.z, t.w, ar, ai, r);
        t = tab[9];  ry8<1>(t.x, t.y, ar, ai, r); rz8<1>(t.z, t.w, ar, ai, r);
        t = tab[10]; ry8<2>(t.x, t.y, ar, ai, r); rz8<2>(t.z, t.w, ar, ai, r);
        t = tab[11]; ry8<3>(t.x, t.y, ar, ai, r); rz8<3>(t.z, t.w, ar, ai, r);
        t = tab[12]; ry8<4>(t.x, t.y, ar, ai, r); rz8<4>(t.z, t.w, ar, ai, r);
        t = tab[13]; ry8<5>(t.x, t.y, ar, ai, r); rz8<5>(t.z, t.w, ar, ai, r);
        t = tab[14]; ry8<6>(t.x, t.y, ar, ai, r); rz8<6>(t.z, t.w, ar, ai, r);
        t = tab[15]; ry8<7>(t.x, t.y, ar, ai, r); rz8<7>(t.z, t.w, ar, ai, r);
    }
    ring8(ar, ai, r);
    {
        float4 t;
        t = tab[16]; ry8<0>(t.x, t.y, ar, ai, r);
        t = tab[17]; ry8<1>(t.x, t.y, ar, ai, r);
        t = tab[18]; ry8<2>(t.x, t.y, ar, ai, r);
        t = tab[19]; ry8<3>(t.x, t.y, ar, ai, r);
        t = tab[20]; ry8<4>(t.x, t.y, ar, ai, r);
        t = tab[21]; ry8<5>(t.x, t.y, ar, ai, r);
        t = tab[22]; ry8<6>(t.x, t.y, ar, ai, r);
        t = tab[23]; ry8<7>(t.x, t.y, ar, ai, r);
    }

    // ---- measurement through folded ring2 ----
    float P[8];
#pragma unroll
    for (int j = 0; j < 8; ++j) P[j] = ar[j] * ar[j] + ai[j] * ai[j];

    // local parities over j bits
    float G01  = (P[0] - P[1] - P[2] + P[3]) + (P[4] - P[5] - P[6] + P[7]);   // j0^j1
    float G012 = (P[0] - P[1] - P[2] + P[3]) - (P[4] - P[5] - P[6] + P[7]);   // j0^j1^j2
    float G12  = (P[0] + P[1] - P[2] - P[3]) - (P[4] + P[5] - P[6] - P[7]);   // j1^j2

    int pr1 = r & 1;
    int pr2 = (r ^ (r >> 1)) & 1;
    int pr3 = (r ^ (r >> 1) ^ (r >> 2)) & 1;
    int pr4 = (r ^ (r >> 1) ^ (r >> 2) ^ (r >> 3)) & 1;
    int pr5 = (r ^ (r >> 1) ^ (r >> 2) ^ (r >> 3) ^ (r >> 4)) & 1;

    float z0 = halfsum31(pr5 ? -G12  : G12);
    float z1 = halfsum31(G01);
    float z2 = halfsum31(G012);
    float z3 = halfsum31(pr1 ? -G012 : G012);
    float z4 = halfsum31(pr2 ? -G012 : G012);
    float z5 = halfsum31(pr3 ? -G012 : G012);
    float z6 = halfsum31(pr4 ? -G012 : G012);
    float z7 = halfsum31(pr5 ? -G012 : G012);

    if (r == 31) {
        *(float4*)&z_lds[sl][0] = make_float4(z0, z1, z2, z3);
        *(float4*)&z_lds[sl][4] = make_float4(z4, z5, z6, z7);
    }
    __syncthreads();

    // ---- MLP phase 1: h[8][64]; thread t -> sample t>>5, 2 cols (t&31)*2 ----
    {
        int s_l = tid >> 5;
        int i_l = (tid & 31) * 2;
        float4 za = *(const float4*)&z_lds[s_l][0];
        float4 zb = *(const float4*)&z_lds[s_l][4];
        float zq[8] = {za.x, za.y, za.z, za.w, zb.x, zb.y, zb.z, zb.w};
        float2 acc = *(const float2*)(b1 + i_l);
#pragma unroll
        for (int q = 0; q < 8; ++q) {
            float2 w = *(const float2*)(W1 + q * 64 + i_l);
            acc.x += zq[q] * w.x;
            acc.y += zq[q] * w.y;
        }
        acc.x = fmaxf(acc.x, 0.f);
        acc.y = fmaxf(acc.y, 0.f);
        *(float2*)&h_lds[s_l][i_l] = acc;
    }
    __syncthreads();

    // ---- MLP phase 2: 2 samples x 4 cols per thread ----
    int sg = tid >> 6;                  // 0..3 -> samples sg*2, sg*2+1
    int c4 = (tid & 63) * 4;
    float4 bb = *(const float4*)(b2 + c4);
    float4 a0 = bb, a1 = bb;
    const int sO = sg * 2;

#pragma unroll 2
    for (int i4 = 0; i4 < 16; ++i4) {
        const float* wrow = W2 + i4 * 4 * 256 + c4;
        float4 w0 = *(const float4*)(wrow);
        float4 w1 = *(const float4*)(wrow + 256);
        float4 w2 = *(const float4*)(wrow + 512);
        float4 w3 = *(const float4*)(wrow + 768);
        float4 h0 = *(const float4*)&h_lds[sO + 0][i4 * 4];
        float4 h1 = *(const float4*)&h_lds[sO + 1][i4 * 4];

        a0.x += h0.x*w0.x + h0.y*w1.x + h0.z*w2.x + h0.w*w3.x;
        a0.y += h0.x*w0.y + h0.y*w1.y + h0.z*w2.y + h0.w*w3.y;
        a0.z += h0.x*w0.z + h0.y*w1.z + h0.z*w2.z + h0.w*w3.z;
        a0.w += h0.x*w0.w + h0.y*w1.w + h0.z*w2.w + h0.w*w3.w;

        a1.x += h1.x*w0.x + h1.y*w1.x + h1.z*w2.x + h1.w*w3.x;
        a1.y += h1.x*w0.y + h1.y*w1.y + h1.z*w2.y + h1.w*w3.y;
        a1.z += h1.x*w0.z + h1.y*w1.z + h1.z*w2.z + h1.w*w3.z;
        a1.w += h1.x*w0.w + h1.y*w1.w + h1.z*w2.w + h1.w*w3.w;
    }

    int srow = sbase + sO;
    if (srow + 0 < B) *(float4*)(out + (srow + 0) * 256 + c4) = a0;
    if (srow + 1 < B) *(float4*)(out + (srow + 1) * 256 + c4) = a1;
}

extern "C" void kernel_launch(void* const* d_in, const int* in_sizes, int n_in,
                              void* d_out, int out_size, void* d_ws, size_t ws_size,
                              hipStream_t stream) {
    const float* x  = (const float*)d_in[0];
    const float* qw = (const float*)d_in[1];
    const float* W1 = (const float*)d_in[2];
    const float* b1 = (const float*)d_in[3];
    const float* W2 = (const float*)d_in[4];
    const float* b2 = (const float*)d_in[5];
    float* out = (float*)d_out;

    int B = in_sizes[0] / NQ;           // 8192

    qfused<<<(B + 7) / 8, 256, 0, stream>>>(x, qw, W1, b1, W2, b2, out, B);
}

// Round 12
// 20.101 us; speedup vs baseline: 1.2026x; 1.2026x over previous
//
#include <hip/hip_runtime.h>

#define NQ 8
#define NLAYERS 3

typedef unsigned int uint2ev __attribute__((ext_vector_type(2)));
typedef float f2 __attribute__((ext_vector_type(2)));   // (re, im) or generic pair

// ---- row-local xor exchange (16-lane rows), zero DS ops ----
template<int MASK>
__device__ __forceinline__ float xorlane(float v, int r) {
    if constexpr (MASK == 1) {
        return __int_as_float(__builtin_amdgcn_mov_dpp(__float_as_int(v), 0xB1, 0xF, 0xF, false)); // quad_perm [1,0,3,2]
    } else if constexpr (MASK == 2) {
        return __int_as_float(__builtin_amdgcn_mov_dpp(__float_as_int(v), 0x4E, 0xF, 0xF, false)); // quad_perm [2,3,0,1]
    } else if constexpr (MASK == 4) {
        float a = __int_as_float(__builtin_amdgcn_update_dpp(0, __float_as_int(v), 0x114, 0xF, 0xF, false)); // row_shr:4
        float b = __int_as_float(__builtin_amdgcn_update_dpp(0, __float_as_int(v), 0x104, 0xF, 0xF, false)); // row_shl:4
        return (r & 4) ? a : b;
    } else if constexpr (MASK == 8) {
        return __int_as_float(__builtin_amdgcn_mov_dpp(__float_as_int(v), 0x128, 0xF, 0xF, false)); // row_ror:8 == xor 8 in row16
    }
}

template<int MASK>
__device__ __forceinline__ f2 xorlane2(f2 v, int r) {
    f2 o;
    o.x = xorlane<MASK>(v.x, r);
    o.y = xorlane<MASK>(v.y, r);
    return o;
}

// ---- DPP-fused row16 sum; row total lands in lane r=15 of each row ----
template<int CTRL>
__device__ __forceinline__ float dpp_add_stage(float v) {
    int moved = __builtin_amdgcn_update_dpp(0, __float_as_int(v), CTRL, 0xF, 0xF, false);
    return v + __int_as_float(moved);
}
__device__ __forceinline__ float rowsum15(float v) {
    v = dpp_add_stage<0x111>(v);   // row_shr:1
    v = dpp_add_stage<0x112>(v);   // row_shr:2
    v = dpp_add_stage<0x114>(v);   // row_shr:4
    v = dpp_add_stage<0x118>(v);   // row_shr:8
    return v;                      // lane 15 of each 16-row has the row sum
}

__device__ __forceinline__ f2 cmul(f2 a, f2 b) {
    f2 r;
    r.x = a.x * b.x - a.y * b.y;
    r.y = a.x * b.y + a.y * b.x;
    return r;
}

__device__ __forceinline__ f2 splat(float c) { f2 v; v.x = c; v.y = c; return v; }

__device__ __forceinline__ f2 sel2(bool hi, f2 a, f2 b) {
    f2 o;
    o.x = hi ? a.x : b.x;
    o.y = hi ? a.y : b.y;
    return o;
}

// qubits 0..3 -> j bits 0..3 (16 amps/lane); qubits 4..7 -> row-lane bits r0..r3
// Packed RY: same formula on (re,im) simultaneously -> v_pk_* shaped
template<int Q>
__device__ __forceinline__ void ry16(float c, float s, f2 A[16], int r) {
    f2 vc = splat(c), vs = splat(s);
    if constexpr (Q < 4) {
        constexpr int M = 1 << Q;
#pragma unroll
        for (int j = 0; j < 16; ++j) if (!(j & M)) {
            f2 a0 = A[j], a1 = A[j | M];
            A[j]     = vc * a0 - vs * a1;
            A[j | M] = vs * a0 + vc * a1;
        }
    } else {
        constexpr int LM = 1 << (Q - 4);
        f2 vsg = (r & LM) ? vs : (splat(0.f) - vs);
#pragma unroll
        for (int j = 0; j < 16; ++j) {
            f2 p = xorlane2<LM>(A[j], r);
            A[j] = vc * A[j] + vsg * p;
        }
    }
}

// ring1: CNOT(0,1),(1,2),(2,3),(3,4),(4,5),(5,6),(6,7),(7,0)
__device__ __forceinline__ void ring16(f2 A[16], int r) {
    f2 t;
    // (0,1): j0=1 -> flip j1
    t = A[1]; A[1] = A[3]; A[3] = t;
    t = A[5]; A[5] = A[7]; A[7] = t;
    t = A[9]; A[9] = A[11]; A[11] = t;
    t = A[13]; A[13] = A[15]; A[15] = t;
    // (1,2): j1=1 -> flip j2
    t = A[2]; A[2] = A[6]; A[6] = t;
    t = A[3]; A[3] = A[7]; A[7] = t;
    t = A[10]; A[10] = A[14]; A[14] = t;
    t = A[11]; A[11] = A[15]; A[15] = t;
    // (2,3): j2=1 -> flip j3
    t = A[4]; A[4] = A[12]; A[12] = t;
    t = A[5]; A[5] = A[13]; A[13] = t;
    t = A[6]; A[6] = A[14]; A[14] = t;
    t = A[7]; A[7] = A[15]; A[15] = t;
    // (3,4): j3=1 -> flip r0
#pragma unroll
    for (int j = 8; j < 16; ++j) A[j] = xorlane2<1>(A[j], r);
    // (4,5): ctrl r0, tgt r1
    {
        bool hi = (r & 1) != 0;
#pragma unroll
        for (int j = 0; j < 16; ++j) {
            f2 p = xorlane2<2>(A[j], r);
            A[j] = sel2(hi, p, A[j]);
        }
    }
    // (5,6): ctrl r1, tgt r2
    {
        bool hi = (r & 2) != 0;
#pragma unroll
        for (int j = 0; j < 16; ++j) {
            f2 p = xorlane2<4>(A[j], r);
            A[j] = sel2(hi, p, A[j]);
        }
    }
    // (6,7): ctrl r2, tgt r3
    {
        bool hi = (r & 4) != 0;
#pragma unroll
        for (int j = 0; j < 16; ++j) {
            f2 p = xorlane2<8>(A[j], r);
            A[j] = sel2(hi, p, A[j]);
        }
    }
    // (7,0): ctrl r3, tgt j0
    {
        bool hi = (r & 8) != 0;
#pragma unroll
        for (int j = 0; j < 16; j += 2) {
            f2 t0 = A[j], t1 = A[j + 1];
            A[j]     = sel2(hi, t1, t0);
            A[j + 1] = sel2(hi, t0, t1);
        }
    }
}

// ============ FUSED kernel: circuit (4 samples/wave) + MLP, 16 samples/block ============
// Exact reductions: layer0 RY+RZ folded into product state; ring0 deleted via
// selectors s0=j0^r3, s1=j0^j1^r3, s2=j1^j2, s3=j2^j3, s4=j3^r0, s5..7=r-adjacent;
// layer1: (RY x8) then ONE fused product-diagonal (all 8 RZ1 gates commuted
// together); layer2 RZ deleted; ring2 folded into measurement masks.
__global__ __launch_bounds__(256) void qfused(
    const float* __restrict__ x,        // [B,8]
    const float* __restrict__ qw,       // [3,8,2]
    const float* __restrict__ W1,       // [8,64]
    const float* __restrict__ b1,       // [64]
    const float* __restrict__ W2,       // [64,256]
    const float* __restrict__ b2,       // [256]
    float* __restrict__ out,            // [B,256]
    int B)
{
    __shared__ float4 tab[NLAYERS * NQ];
    __shared__ float z_lds[16][8];
    __shared__ float h_lds[16][64];

    int tid = threadIdx.x;
    if (tid < NLAYERS * NQ) {
        float w0 = 0.5f * qw[tid * 2 + 0];
        float w1 = 0.5f * qw[tid * 2 + 1];
        if (tid < 8)
            tab[tid] = make_float4(w0, 0.f, __cosf(w1), __sinf(w1));
        else
            tab[tid] = make_float4(__cosf(w0), __sinf(w0), __cosf(w1), __sinf(w1));
    }
    __syncthreads();

    int lane = tid & 63;
    int wid  = tid >> 6;
    int g    = lane >> 4;               // sample group in wave
    int r    = lane & 15;               // row-lane bits r0..r3
    int sl   = wid * 4 + g;             // sample slot in block (0..15)
    int sbase = blockIdx.x * 16;
    int sample = sbase + sl;
    if (sample >= B) sample = B - 1;    // clamp: all threads reach barriers

    // ---- per-lane encode ----
    const float4* x4 = (const float4*)(x + sample * 8);
    float4 xa = x4[0], xb = x4[1];
    float xs[8] = {xa.x, xa.y, xa.z, xa.w, xb.x, xb.y, xb.z, xb.w};
    float xmin = xs[0], xmax = xs[0];
#pragma unroll
    for (int q = 1; q < 8; ++q) {
        xmin = fminf(xmin, xs[q]);
        xmax = fmaxf(xmax, xs[q]);
    }
    float inv_pi2 = 1.5707963267948966f / (xmax - xmin + 1e-8f);

    float cc[8], ss[8], cw[8], sw[8];
#pragma unroll
    for (int q = 0; q < 8; ++q) {
        float4 t0 = tab[q];
        float a = fmaf(xs[q] - xmin, inv_pi2, t0.x);
        __sincosf(a, &ss[q], &cc[q]);
        cw[q] = t0.z;
        sw[q] = t0.w;
    }

    // f_q(b) = ((b? ss:cc)*cw, (b? +1:-1)*(b? ss:cc)*sw)
    int r0v = r & 1, r3v = (r >> 3) & 1;

    f2 X0[2], X1[2], X2[2], X3[2], X4[2];
#pragma unroll
    for (int k = 0; k < 2; ++k) {
        { int b = k ^ r3v; float rr = b ? ss[0] : cc[0];
          X0[k].x = rr * cw[0]; X0[k].y = (b ? rr : -rr) * sw[0]; }
        { int b = k ^ r3v; float rr = b ? ss[1] : cc[1];
          X1[k].x = rr * cw[1]; X1[k].y = (b ? rr : -rr) * sw[1]; }
        { int b = k;        float rr = b ? ss[2] : cc[2];
          X2[k].x = rr * cw[2]; X2[k].y = (b ? rr : -rr) * sw[2]; }
        { int b = k;        float rr = b ? ss[3] : cc[3];
          X3[k].x = rr * cw[3]; X3[k].y = (b ? rr : -rr) * sw[3]; }
        { int b = k ^ r0v;  float rr = b ? ss[4] : cc[4];
          X4[k].x = rr * cw[4]; X4[k].y = (b ? rr : -rr) * sw[4]; }
    }

    // plane = f5(r0^r1) * f6(r1^r2) * f7(r2^r3)
    f2 pl;
    {
        int b5 = (r ^ (r >> 1)) & 1;
        int b6 = ((r >> 1) ^ (r >> 2)) & 1;
        int b7 = ((r >> 2) ^ (r >> 3)) & 1;
        f2 f5, f6, f7;
        float r5 = b5 ? ss[5] : cc[5];
        f5.x = r5 * cw[5]; f5.y = (b5 ? r5 : -r5) * sw[5];
        float r6 = b6 ? ss[6] : cc[6];
        f6.x = r6 * cw[6]; f6.y = (b6 ? r6 : -r6) * sw[6];
        float r7 = b7 ? ss[7] : cc[7];
        f7.x = r7 * cw[7]; f7.y = (b7 ? r7 : -r7) * sw[7];
        pl = cmul(cmul(f5, f6), f7);
    }

    // PP[j0][j1] = plane * X0[j0] * X1[j0^j1]
    f2 PP[2][2];
    {
        f2 t0 = cmul(pl, X0[0]);
        f2 t1 = cmul(pl, X0[1]);
        PP[0][0] = cmul(t0, X1[0]);
        PP[0][1] = cmul(t0, X1[1]);
        PP[1][0] = cmul(t1, X1[1]);
        PP[1][1] = cmul(t1, X1[0]);
    }
    // Q34[j2][j3] = X3[j2^j3] * X4[j3]
    f2 Q34[2][2];
    Q34[0][0] = cmul(X3[0], X4[0]);
    Q34[0][1] = cmul(X3[1], X4[1]);
    Q34[1][0] = cmul(X3[1], X4[0]);
    Q34[1][1] = cmul(X3[0], X4[1]);
    // R[j1][j2][j3] = X2[j1^j2] * Q34[j2][j3]
    f2 R[2][2][2];
#pragma unroll
    for (int j1 = 0; j1 < 2; ++j1)
#pragma unroll
        for (int j2 = 0; j2 < 2; ++j2)
#pragma unroll
            for (int j3 = 0; j3 < 2; ++j3)
                R[j1][j2][j3] = cmul(X2[j1 ^ j2], Q34[j2][j3]);

    f2 A[16];
#pragma unroll
    for (int j3 = 0; j3 < 2; ++j3)
#pragma unroll
        for (int j2 = 0; j2 < 2; ++j2)
#pragma unroll
            for (int j1 = 0; j1 < 2; ++j1)
#pragma unroll
                for (int j0 = 0; j0 < 2; ++j0) {
                    int j = j0 + 2 * j1 + 4 * j2 + 8 * j3;
                    A[j] = cmul(PP[j0][j1], R[j1][j2][j3]);
                }

    // ---- layer 1: RY x8 (RZ commuted out) ----
    {
        float4 t;
        t = tab[8];  ry16<0>(t.x, t.y, A, r);
        t = tab[9];  ry16<1>(t.x, t.y, A, r);
        t = tab[10]; ry16<2>(t.x, t.y, A, r);
        t = tab[11]; ry16<3>(t.x, t.y, A, r);
        t = tab[12]; ry16<4>(t.x, t.y, A, r);
        t = tab[13]; ry16<5>(t.x, t.y, A, r);
        t = tab[14]; ry16<6>(t.x, t.y, A, r);
        t = tab[15]; ry16<7>(t.x, t.y, A, r);
    }

    // ---- fused RZ1 product-diagonal: d(i) = prod_q (cz_q, ±sz_q) ----
    {
        // lane part: qubits 4..7 -> bits r0..r3
        f2 L;
        {
            float4 t4 = tab[12], t5 = tab[13], t6 = tab[14], t7 = tab[15];
            f2 d4, d5, d6, d7;
            d4.x = t4.z; d4.y = (r & 1) ? t4.w : -t4.w;
            d5.x = t5.z; d5.y = (r & 2) ? t5.w : -t5.w;
            d6.x = t6.z; d6.y = (r & 4) ? t6.w : -t6.w;
            d7.x = t7.z; d7.y = (r & 8) ? t7.w : -t7.w;
            L = cmul(cmul(d4, d5), cmul(d6, d7));
        }
        // local part tables
        float4 t0q = tab[8], t1q = tab[9], t2q = tab[10], t3q = tab[11];
        f2 d0n, d0p, d1n, d1p, d2n, d2p, d3n, d3p;
        d0n.x = t0q.z; d0n.y = -t0q.w;  d0p.x = t0q.z; d0p.y = t0q.w;
        d1n.x = t1q.z; d1n.y = -t1q.w;  d1p.x = t1q.z; d1p.y = t1q.w;
        d2n.x = t2q.z; d2n.y = -t2q.w;  d2p.x = t2q.z; d2p.y = t2q.w;
        d3n.x = t3q.z; d3n.y = -t3q.w;  d3p.x = t3q.z; d3p.y = t3q.w;

        f2 t01[4];
        {
            f2 l0 = cmul(L, d0n), l1 = cmul(L, d0p);
            t01[0] = cmul(l0, d1n);   // j0=0, j1=0
            t01[1] = cmul(l1, d1n);   // j0=1, j1=0
            t01[2] = cmul(l0, d1p);   // j0=0, j1=1
            t01[3] = cmul(l1, d1p);   // j0=1, j1=1
        }
        f2 m23[4];
        m23[0] = cmul(d2n, d3n);      // j2=0, j3=0
        m23[1] = cmul(d2p, d3n);      // j2=1, j3=0
        m23[2] = cmul(d2n, d3p);      // j2=0, j3=1
        m23[3] = cmul(d2p, d3p);      // j2=1, j3=1

#pragma unroll
        for (int j = 0; j < 16; ++j) {
            f2 D = cmul(t01[j & 3], m23[j >> 2]);
            A[j] = cmul(A[j], D);
        }
    }

    // ---- ring 1 ----
    ring16(A, r);

    // ---- layer 2: RY only ----
    {
        float4 t;
        t = tab[16]; ry16<0>(t.x, t.y, A, r);
        t = tab[17]; ry16<1>(t.x, t.y, A, r);
        t = tab[18]; ry16<2>(t.x, t.y, A, r);
        t = tab[19]; ry16<3>(t.x, t.y, A, r);
        t = tab[20]; ry16<4>(t.x, t.y, A, r);
        t = tab[21]; ry16<5>(t.x, t.y, A, r);
        t = tab[22]; ry16<6>(t.x, t.y, A, r);
        t = tab[23]; ry16<7>(t.x, t.y, A, r);
    }

    // ---- measurement through folded ring2 ----
    float P[16];
#pragma unroll
    for (int j = 0; j < 16; ++j) P[j] = A[j].x * A[j].x + A[j].y * A[j].y;

    float Sp[8], Dp[8];
#pragma unroll
    for (int k = 0; k < 8; ++k) {
        Sp[k] = P[2 * k] + P[2 * k + 1];
        Dp[k] = P[2 * k] - P[2 * k + 1];
    }
    float U0 = ((Sp[0] - Sp[1]) - (Sp[2] - Sp[3])) - ((Sp[4] - Sp[5]) - (Sp[6] - Sp[7]));
    float U3 = ((Dp[0] - Dp[1]) - (Dp[2] - Dp[3])) - ((Dp[4] - Dp[5]) - (Dp[6] - Dp[7]));
    float U1 = (Dp[0] - Dp[1]) + (Dp[2] - Dp[3]) + (Dp[4] - Dp[5]) + (Dp[6] - Dp[7]);
    float U2 = ((Dp[0] - Dp[1]) - (Dp[2] - Dp[3])) + ((Dp[4] - Dp[5]) - (Dp[6] - Dp[7]));

    int p1 = r & 1;
    int p2 = (r ^ (r >> 1)) & 1;
    int p3 = (r ^ (r >> 1) ^ (r >> 2)) & 1;
    int p4 = (r ^ (r >> 1) ^ (r >> 2) ^ (r >> 3)) & 1;

    float z0 = rowsum15(p4 ? -U0 : U0);
    float z1 = rowsum15(U1);
    float z2 = rowsum15(U2);
    float z3 = rowsum15(U3);
    float z4 = rowsum15(p1 ? -U3 : U3);
    float z5 = rowsum15(p2 ? -U3 : U3);
    float z6 = rowsum15(p3 ? -U3 : U3);
    float z7 = rowsum15(p4 ? -U3 : U3);

    if (r == 15) {
        *(float4*)&z_lds[sl][0] = make_float4(z0, z1, z2, z3);
        *(float4*)&z_lds[sl][4] = make_float4(z4, z5, z6, z7);
    }
    __syncthreads();

    // ---- MLP phase 1: h[16][64] tile ----
    {
        int s_l = tid >> 4;
        int i_l = (tid & 15) * 4;
        float4 za = *(const float4*)&z_lds[s_l][0];
        float4 zb = *(const float4*)&z_lds[s_l][4];
        float zq[8] = {za.x, za.y, za.z, za.w, zb.x, zb.y, zb.z, zb.w};
        float4 acc = *(const float4*)(b1 + i_l);
#pragma unroll
        for (int q = 0; q < 8; ++q) {
            float4 w = *(const float4*)(W1 + q * 64 + i_l);
            acc.x += zq[q] * w.x; acc.y += zq[q] * w.y;
            acc.z += zq[q] * w.z; acc.w += zq[q] * w.w;
        }
        acc.x = fmaxf(acc.x, 0.f); acc.y = fmaxf(acc.y, 0.f);
        acc.z = fmaxf(acc.z, 0.f); acc.w = fmaxf(acc.w, 0.f);
        *(float4*)&h_lds[s_l][i_l] = acc;
    }
    __syncthreads();

    // ---- MLP phase 2: out = h @ W2 + b2 ; 4 samples x 4 cols per thread ----
    int sg = tid >> 6;
    int c4 = (tid & 63) * 4;
    float4 bb = *(const float4*)(b2 + c4);
    float4 a0 = bb, a1 = bb, a2 = bb, a3 = bb;
    const int sO = sg * 4;

#pragma unroll 2
    for (int i4 = 0; i4 < 16; ++i4) {
        const float* wrow = W2 + i4 * 4 * 256 + c4;
        float4 w0 = *(const float4*)(wrow);
        float4 w1 = *(const float4*)(wrow + 256);
        float4 w2 = *(const float4*)(wrow + 512);
        float4 w3 = *(const float4*)(wrow + 768);
        float4 h0 = *(const float4*)&h_lds[sO + 0][i4 * 4];
        float4 h1 = *(const float4*)&h_lds[sO + 1][i4 * 4];
        float4 h2 = *(const float4*)&h_lds[sO + 2][i4 * 4];
        float4 h3 = *(const float4*)&h_lds[sO + 3][i4 * 4];

        a0.x += h0.x*w0.x + h0.y*w1.x + h0.z*w2.x + h0.w*w3.x;
        a0.y += h0.x*w0.y + h0.y*w1.y + h0.z*w2.y + h0.w*w3.y;
        a0.z += h0.x*w0.z + h0.y*w1.z + h0.z*w2.z + h0.w*w3.z;
        a0.w += h0.x*w0.w + h0.y*w1.w + h0.z*w2.w + h0.w*w3.w;

        a1.x += h1.x*w0.x + h1.y*w1.x + h1.z*w2.x + h1.w*w3.x;
        a1.y += h1.x*w0.y + h1.y*w1.y + h1.z*w2.y + h1.w*w3.y;
        a1.z += h1.x*w0.z + h1.y*w1.z + h1.z*w2.z + h1.w*w3.z;
        a1.w += h1.x*w0.w + h1.y*w1.w + h1.z*w2.w + h1.w*w3.w;

        a2.x += h2.x*w0.x + h2.y*w1.x + h2.z*w2.x + h2.w*w3.x;
        a2.y += h2.x*w0.y + h2.y*w1.y + h2.z*w2.y + h2.w*w3.y;
        a2.z += h2.x*w0.z + h2.y*w1.z + h2.z*w2.z + h2.w*w3.z;
        a2.w += h2.x*w0.w + h2.y*w1.w + h2.z*w2.w + h2.w*w3.w;

        a3.x += h3.x*w0.x + h3.y*w1.x + h3.z*w2.x + h3.w*w3.x;
        a3.y += h3.x*w0.y + h3.y*w1.y + h3.z*w2.y + h3.w*w3.y;
        a3.z += h3.x*w0.z + h3.y*w1.z + h3.z*w2.z + h3.w*w3.z;
        a3.w += h3.x*w0.w + h3.y*w1.w + h3.z*w2.w + h3.w*w3.w;
    }

    int srow = sbase + sO;
    if (srow + 0 < B) *(float4*)(out + (srow + 0) * 256 + c4) = a0;
    if (srow + 1 < B) *(float4*)(out + (srow + 1) * 256 + c4) = a1;
    if (srow + 2 < B) *(float4*)(out + (srow + 2) * 256 + c4) = a2;
    if (srow + 3 < B) *(float4*)(out + (srow + 3) * 256 + c4) = a3;
}

extern "C" void kernel_launch(void* const* d_in, const int* in_sizes, int n_in,
                              void* d_out, int out_size, void* d_ws, size_t ws_size,
                              hipStream_t stream) {
    const float* x  = (const float*)d_in[0];
    const float* qw = (const float*)d_in[1];
    const float* W1 = (const float*)d_in[2];
    const float* b1 = (const float*)d_in[3];
    const float* W2 = (const float*)d_in[4];
    const float* b2 = (const float*)d_in[5];
    float* out = (float*)d_out;

    int B = in_sizes[0] / NQ;           // 8192

    qfused<<<(B + 15) / 16, 256, 0, stream>>>(x, qw, W1, b1, W2, b2, out, B);
}